// Round 6
// baseline (2631.230 us; speedup 1.0000x reference)
//
#include <hip/hip_runtime.h>

#define DT_F 0.01f
#define EPS_F 1e-5f
#define NEG_INF_I (-1073741824)

typedef _Float16 f16;
typedef _Float16 f16x8 __attribute__((ext_vector_type(8)));
typedef float f32x4 __attribute__((ext_vector_type(4)));

#define MFMA16(a, b, c) __builtin_amdgcn_mfma_f32_16x16x32_f16((a), (b), (c), 0, 0, 0)

__device__ __forceinline__ float sigm(float x) { return 1.0f / (1.0f + __expf(-x)); }
__device__ __forceinline__ float tanhf_fast(float x) {
  float e = __expf(-2.0f * fabsf(x));
  float t = (1.0f - e) / (1.0f + e);
  return x < 0.0f ? -t : t;
}

// evtab[k*B + sid] = (last obs index in event k's window with sample_ids==sid) + 1, or 0.
__global__ void build_evtab_kernel(const int* __restrict__ sample_ids,
                                   const int* __restrict__ time_ptr,
                                   int* __restrict__ evtab, int B, int ope) {
  int k = blockIdx.x;
  int base = time_ptr[k];
  for (int t = threadIdx.x; t < ope; t += blockDim.x) {
    int obs = base + t;
    int sid = sample_ids[obs];
    atomicMax(&evtab[k * B + sid], obs + 1);   // last occurrence wins
  }
}

// Pack weights into per-lane MFMA B-fragment images (16x16x32 f16), HW-verified in R5.
//   f in [0,24):  ODE   (g,t,kf): f = 8g + 2t + kf, W = {ghr,ghz,ghh}[n][k]
//   f in [24,48): BayesH (g,t,kf): f = 24 + 8g + 2t + kf, W = gb_Whh[(64g+n)][k]
//   f in [48,60): BayesX (g,t):    f = 48 + 4g + t, W = gb_Wih[(64g+n)][kx], kx<IN else 0
__global__ void pack_frags_kernel(const float* __restrict__ ghr,
                                  const float* __restrict__ ghz,
                                  const float* __restrict__ ghh,
                                  const float* __restrict__ gbWhh,
                                  const float* __restrict__ gbWih,
                                  f16* __restrict__ frags, int IN) {
  int f = blockIdx.x;       // 0..59
  int l = threadIdx.x;      // 0..63
  for (int j = 0; j < 8; ++j) {
    float v = 0.0f;
    if (f < 48) {
      int fb = (f < 24) ? f : f - 24;
      int g = fb >> 3, t = (fb >> 1) & 3, kf = fb & 1;
      int n = 16 * t + (l & 15);
      int k = 8 * (l >> 4) + j + 32 * kf;
      if (f < 24) {
        const float* src = (g == 0) ? ghr : ((g == 1) ? ghz : ghh);
        v = src[n * 64 + k];
      } else {
        v = gbWhh[(g * 64 + n) * 64 + k];
      }
    } else {
      int fb = f - 48;
      int g = fb >> 2, t = fb & 3;
      int n = 16 * t + (l & 15);
      int kx = 8 * (l >> 4) + j;
      v = (kx < IN) ? gbWih[(g * 64 + n) * IN + kx] : 0.0f;
    }
    frags[(long)f * 512 + l * 8 + j] = (f16)v;
  }
}

// ONE WAVE per 16 samples. Zero barriers in the main loop (same-wave LDS
// ordering). All 60 weight fragments in VGPRs. LDS images XOR-row-swizzled.
__global__ __launch_bounds__(64, 1) void evolve_kernel(
    const float* __restrict__ time_uniq,
    const float* __restrict__ X,
    const float* __restrict__ covs,
    const float* __restrict__ cov_W1, const float* __restrict__ cov_b1,
    const float* __restrict__ cov_W2, const float* __restrict__ cov_b2,
    const float* __restrict__ gb_bih, const float* __restrict__ gb_bhh,
    const float* __restrict__ gx_b,
    const f16* __restrict__ gfrags,
    const int* __restrict__ evtab,
    float* __restrict__ hpath,
    int B, int NE, int n_steps, int IN, int COV)
{
  __shared__ __align__(16) f16 sHimg[2 * 512];
  __shared__ __align__(16) f16 sRHimg[2 * 512];
  __shared__ __align__(16) f16 sXimg[512];
  __shared__ int sStep[1024];
  __shared__ float sRelu[16][65];

  const int lane = threadIdx.x;           // 0..63
  const int b0 = blockIdx.x * 16;
  const int col = lane & 15;
  const int mrow = 4 * (lane >> 4);

  // ---- event schedule: wave-parallel prefix-max (replaces serial lane-0 pass)
  // serial recurrence s[e]=max(f[e], s[e-1]+1)  <=>  s[e]=e+max_{e'<=e}(f[e']-e')
  {
    int pm = NEG_INF_I;
    int loc[16];
#pragma unroll
    for (int j = 0; j < 16; ++j) {
      int e = lane * 16 + j;
      int gv = NEG_INF_I;
      if (e < NE && e < 1024) {
        float tu = time_uniq[e];
        int k0 = (int)floorf((tu - EPS_F) * 100.0f) - 2;
        if (k0 < 0) k0 = 0;
        while ((float)k0 * DT_F + EPS_F < tu) ++k0;   // exact fp32 semantics
        gv = k0 - e;
      }
      pm = max(pm, gv);
      loc[j] = pm;
    }
    int tot = pm;
#pragma unroll
    for (int off = 1; off < 64; off <<= 1) {
      int v = __shfl_up(tot, off);
      if (lane >= off) tot = max(tot, v);
    }
    int excl = __shfl_up(tot, 1);
    if (lane == 0) excl = NEG_INF_I;
#pragma unroll
    for (int j = 0; j < 16; ++j) {
      int e = lane * 16 + j;
      sStep[e] = e + max(loc[j], excl);
    }
  }

  // ---- covariate hidden layer ----
  for (int idx = lane; idx < 16 * 64; idx += 64) {
    int sm = idx >> 6, u = idx & 63;
    float a = cov_b1[u];
    if (b0 + sm < B)
      for (int c = 0; c < COV; ++c)
        a = fmaf(covs[(b0 + sm) * COV + c], cov_W1[u * COV + c], a);
    sRelu[sm][u] = fmaxf(a, 0.0f);
  }
  for (int i = lane; i < 512; i += 64) sXimg[i] = (f16)0.0f;
  __syncthreads();   // init only (single wave; cheap)

  // ---- swizzled image offsets: write (t,i) -> precomputed; read at bi(lane) ----
  const int rdswz = ((lane ^ (lane >> 3)) & 63) * 8;
  int woff[4][4];
#pragma unroll
  for (int t = 0; t < 4; ++t)
#pragma unroll
    for (int i = 0; i < 4; ++i) {
      int kk = 16 * t + col, m = mrow + i;
      int R = m + ((kk & 31) >> 3) * 16;
      woff[t][i] = (kk >> 5) * 512 + ((R ^ (R >> 3)) & 63) * 8 + (kk & 7);
    }

  // ---- h0 = tanh(relu @ W2^T + b2) ----
  float h[4][4];
#pragma unroll
  for (int t = 0; t < 4; ++t)
#pragma unroll
    for (int i = 0; i < 4; ++i) {
      float a = cov_b2[16 * t + col];
      for (int j = 0; j < 64; ++j)
        a = fmaf(sRelu[mrow + i][j], cov_W2[(16 * t + col) * 64 + j], a);
      h[t][i] = tanhf_fast(a);
      sHimg[woff[t][i]] = (f16)h[t][i];
    }

  // ---- ALL weight fragments into registers (60 x f16x8 = 240 VGPR) ----
  const f16x8* gf = (const f16x8*)gfrags;
  f16x8 Fr[4][2], Fz[4][2], Fu[4][2], Br[4][2], Bz[4][2], Bn[4][2], Xw[3][4];
#pragma unroll
  for (int t = 0; t < 4; ++t)
#pragma unroll
    for (int kf = 0; kf < 2; ++kf) {
      Fr[t][kf] = gf[(2 * t + kf) * 64 + lane];
      Fz[t][kf] = gf[(8 + 2 * t + kf) * 64 + lane];
      Fu[t][kf] = gf[(16 + 2 * t + kf) * 64 + lane];
      Br[t][kf] = gf[(24 + 2 * t + kf) * 64 + lane];
      Bz[t][kf] = gf[(32 + 2 * t + kf) * 64 + lane];
      Bn[t][kf] = gf[(40 + 2 * t + kf) * 64 + lane];
    }
#pragma unroll
  for (int g = 0; g < 3; ++g)
#pragma unroll
    for (int t = 0; t < 4; ++t)
      Xw[g][t] = gf[(48 + 4 * g + t) * 64 + lane];

  float xrb[4], xzb[4], xhb[4], cbr[4], cbz[4], binv[4], bhnv[4];
#pragma unroll
  for (int t = 0; t < 4; ++t) {
    int n = 16 * t + col;
    xrb[t] = gx_b[n]; xzb[t] = gx_b[64 + n]; xhb[t] = gx_b[128 + n];
    cbr[t] = gb_bih[n] + gb_bhh[n];
    cbz[t] = gb_bih[64 + n] + gb_bhh[64 + n];
    binv[t] = gb_bih[128 + n]; bhnv[t] = gb_bhh[128 + n];
  }

  // ---- event prefetch (2 slots) + staging ----
  int ev0 = 0, ev1 = 0;
  float2 xp0 = make_float2(0.f, 0.f), xp1 = make_float2(0.f, 0.f);
  auto issue_pf = [&](int e, int& evR, float2& xpR) {
    evR = 0; xpR.x = 0.f; xpR.y = 0.f;
    if (e < NE && e < 1024) {
      if (lane < 16 && b0 + lane < B) evR = evtab[(long)e * B + b0 + lane];
      int vs = __shfl(evR, lane >> 2);
      int c0 = 2 * (lane & 3);
      if (vs > 0) {
        const float* xp = X + (long)(vs - 1) * IN;
        if (c0 < IN)     xpR.x = xp[c0];
        if (c0 + 1 < IN) xpR.y = xp[c0 + 1];
      }
    }
  };
  auto stage = [&](int evv, float2 x2) -> unsigned {
    int m = lane >> 2, c0 = 2 * (lane & 3);
    sXimg[m * 8 + c0]     = (f16)x2.x;
    sXimg[m * 8 + c0 + 1] = (f16)x2.y;
    unsigned long long bal = __ballot((lane < 16) && (evv > 0));
    return (unsigned)(bal & 0xFFFFull);
  };

  unsigned mask_cur = 0;
  int e_next = 0;
  int s_next = 0x7fffffff;
  if (NE > 0) {
    s_next = sStep[0];
    issue_pf(0, ev0, xp0);
    issue_pf(1, ev1, xp1);
    mask_cur = stage(ev0, xp0);
  }

#pragma unroll 1
  for (int k = 0; k < n_steps; ++k) {
    f16x8 aH0 = *(const f16x8*)&sHimg[rdswz];
    f16x8 aH1 = *(const f16x8*)&sHimg[512 + rdswz];

    if (k == s_next) {                       // wave-uniform event step
      if (mask_cur) {
        f16x8 aX = *(const f16x8*)&sXimg[lane * 8];
#pragma unroll
        for (int t = 0; t < 4; ++t) {
          f32x4 ra = {0.f, 0.f, 0.f, 0.f}, za = ra, hna = ra, ina = ra;
          ra  = MFMA16(aH0, Br[t][0], ra);  ra  = MFMA16(aH1, Br[t][1], ra);
          ra  = MFMA16(aX,  Xw[0][t], ra);
          za  = MFMA16(aH0, Bz[t][0], za);  za  = MFMA16(aH1, Bz[t][1], za);
          za  = MFMA16(aX,  Xw[1][t], za);
          hna = MFMA16(aH0, Bn[t][0], hna); hna = MFMA16(aH1, Bn[t][1], hna);
          ina = MFMA16(aX,  Xw[2][t], ina);
#pragma unroll
          for (int i = 0; i < 4; ++i) {
            float rb = sigm(ra[i] + cbr[t]);
            float zb = sigm(za[i] + cbz[t]);
            float nb = tanhf_fast((ina[i] + binv[t]) + rb * (hna[i] + bhnv[t]));
            float hnew = (1.0f - zb) * nb + zb * h[t][i];
            if ((mask_cur >> (mrow + i)) & 1) h[t][i] = hnew;
            sHimg[woff[t][i]] = (f16)h[t][i];
          }
        }
        aH0 = *(const f16x8*)&sHimg[rdswz];            // same-wave RAW: auto waitcnt
        aH1 = *(const f16x8*)&sHimg[512 + rdswz];
      }
      ++e_next;
      if (e_next < NE && e_next < 1024) {
        s_next = sStep[e_next];
        if (e_next & 1) { mask_cur = stage(ev1, xp1); issue_pf(e_next + 1, ev0, xp0); }
        else            { mask_cur = stage(ev0, xp0); issue_pf(e_next + 1, ev1, xp1); }
      } else {
        s_next = 0x7fffffff;
        mask_cur = 0;
      }
    }

    // h_rec (post-event, pre-ODE)
    {
      long basep = ((long)k * B + b0) * 64;
#pragma unroll
      for (int t = 0; t < 4; ++t)
#pragma unroll
        for (int i = 0; i < 4; ++i)
          if (b0 + mrow + i < B)
            hpath[basep + (long)(mrow + i) * 64 + 16 * t + col] = h[t][i];
    }

    // ---- ODE phase 1: r,z (16 MFMA) ----
    float zg[4][4];
#pragma unroll
    for (int t = 0; t < 4; ++t) {
      f32x4 ra = {0.f, 0.f, 0.f, 0.f}, za = ra;
      ra = MFMA16(aH0, Fr[t][0], ra); ra = MFMA16(aH1, Fr[t][1], ra);
      za = MFMA16(aH0, Fz[t][0], za); za = MFMA16(aH1, Fz[t][1], za);
#pragma unroll
      for (int i = 0; i < 4; ++i) {
        float r = sigm(ra[i] + xrb[t]);
        zg[t][i] = sigm(za[i] + xzb[t]);
        sRHimg[woff[t][i]] = (f16)(r * h[t][i]);
      }
    }
    f16x8 aR0 = *(const f16x8*)&sRHimg[rdswz];
    f16x8 aR1 = *(const f16x8*)&sRHimg[512 + rdswz];

    // ---- ODE phase 2: u (8 MFMA) + state update ----
#pragma unroll
    for (int t = 0; t < 4; ++t) {
      f32x4 ua = {0.f, 0.f, 0.f, 0.f};
      ua = MFMA16(aR0, Fu[t][0], ua); ua = MFMA16(aR1, Fu[t][1], ua);
#pragma unroll
      for (int i = 0; i < 4; ++i) {
        float u = tanhf_fast(ua[i] + xhb[t]);
        h[t][i] = fmaf(DT_F * (1.0f - zg[t][i]), u - h[t][i], h[t][i]);
        sHimg[woff[t][i]] = (f16)h[t][i];
      }
    }
  }

  // h_last
  {
    long basep = ((long)n_steps * B + b0) * 64;
#pragma unroll
    for (int t = 0; t < 4; ++t)
#pragma unroll
      for (int i = 0; i < 4; ++i)
        if (b0 + mrow + i < B)
          hpath[basep + (long)(mrow + i) * 64 + 16 * t + col] = h[t][i];
  }
}

// out[row] = relu(h[row] @ W1^T + b1) @ W2^T + b2, rows = (n_steps+1)*B
__global__ __launch_bounds__(256, 2) void head_kernel(
    const float* __restrict__ hpath, const float* __restrict__ W1,
    const float* __restrict__ b1, const float* __restrict__ W2,
    const float* __restrict__ b2, float* __restrict__ out, long nrows)
{
  __shared__ __align__(16) float sW1[64 * 128];
  __shared__ __align__(16) float sH[64 * 128];
  int tid = threadIdx.x;
  for (int idx = tid; idx < 128 * 64; idx += 256) {
    int oc = idx >> 6, j = idx & 63;
    sW1[j * 128 + oc] = W1[idx];
  }
  long row0 = (long)blockIdx.x * 128;
  for (int idx = tid; idx < 128 * 64; idx += 256) {
    int r = idx >> 6, j = idx & 63;
    long row = row0 + r;
    sH[j * 128 + r] = (row < nrows) ? hpath[row * 64 + j] : 0.0f;
  }
  __syncthreads();

  int tr = tid >> 4, tc = tid & 15;
  int r0 = tr * 8, oc0 = tc * 8;
  float acc[8][8];
#pragma unroll
  for (int s = 0; s < 8; ++s)
#pragma unroll
    for (int u = 0; u < 8; ++u) acc[s][u] = 0.0f;

#pragma unroll 4
  for (int j = 0; j < 64; ++j) {
    float4 ha = *(const float4*)&sH[j * 128 + r0];
    float4 hb = *(const float4*)&sH[j * 128 + r0 + 4];
    float4 wa = *(const float4*)&sW1[j * 128 + oc0];
    float4 wb = *(const float4*)&sW1[j * 128 + oc0 + 4];
    float hv[8] = {ha.x, ha.y, ha.z, ha.w, hb.x, hb.y, hb.z, hb.w};
    float wv[8] = {wa.x, wa.y, wa.z, wa.w, wb.x, wb.y, wb.z, wb.w};
#pragma unroll
    for (int s = 0; s < 8; ++s)
#pragma unroll
      for (int u = 0; u < 8; ++u)
        acc[s][u] = fmaf(hv[s], wv[u], acc[s][u]);
  }

  float p[8][2];
#pragma unroll
  for (int s = 0; s < 8; ++s) { p[s][0] = 0.0f; p[s][1] = 0.0f; }
#pragma unroll
  for (int u = 0; u < 8; ++u) {
    float b1v = b1[oc0 + u];
    float w2a = W2[oc0 + u];
    float w2b = W2[128 + oc0 + u];
#pragma unroll
    for (int s = 0; s < 8; ++s) {
      float o = fmaxf(acc[s][u] + b1v, 0.0f);
      p[s][0] = fmaf(o, w2a, p[s][0]);
      p[s][1] = fmaf(o, w2b, p[s][1]);
    }
  }
#pragma unroll
  for (int off = 1; off < 16; off <<= 1) {
#pragma unroll
    for (int s = 0; s < 8; ++s) {
      p[s][0] += __shfl_xor(p[s][0], off);
      p[s][1] += __shfl_xor(p[s][1], off);
    }
  }
  if (tc == 0) {
    float b20 = b2[0], b21 = b2[1];
#pragma unroll
    for (int s = 0; s < 8; ++s) {
      long row = row0 + r0 + s;
      if (row < nrows) {
        out[row * 2 + 0] = p[s][0] + b20;
        out[row * 2 + 1] = p[s][1] + b21;
      }
    }
  }
}

extern "C" void kernel_launch(void* const* d_in, const int* in_sizes, int n_in,
                              void* d_out, int out_size, void* d_ws, size_t ws_size,
                              hipStream_t stream) {
  const float* time_uniq  = (const float*)d_in[0];
  const int*   time_ptr   = (const int*)d_in[1];
  const float* X          = (const float*)d_in[2];
  const int*   sample_ids = (const int*)d_in[3];
  const float* covs       = (const float*)d_in[4];
  const float* cov_W1     = (const float*)d_in[6];
  const float* cov_b1     = (const float*)d_in[7];
  const float* cov_W2     = (const float*)d_in[8];
  const float* cov_b2     = (const float*)d_in[9];
  const float* gb_Wih     = (const float*)d_in[10];
  const float* gb_Whh     = (const float*)d_in[11];
  const float* gb_bih     = (const float*)d_in[12];
  const float* gb_bhh     = (const float*)d_in[13];
  const float* gx_b       = (const float*)d_in[15];
  const float* ghr_W      = (const float*)d_in[16];
  const float* ghz_W      = (const float*)d_in[17];
  const float* ghh_W      = (const float*)d_in[18];
  const float* out_W1     = (const float*)d_in[19];
  const float* out_b1     = (const float*)d_in[20];
  const float* out_W2     = (const float*)d_in[21];
  const float* out_b2     = (const float*)d_in[22];

  int NE   = in_sizes[0];
  int TOT  = in_sizes[3];
  int IN   = in_sizes[2] / TOT;
  int CH   = in_sizes[7];
  int COV  = in_sizes[6] / CH;
  int B    = in_sizes[4] / COV;
  int OUTD = in_sizes[22];
  int n_steps = out_size / (B * OUTD) - 1;
  int OPE  = TOT / NE;

  char* ws = (char*)d_ws;
  int* evtab = (int*)ws;
  size_t evbytes = (size_t)NE * (size_t)B * sizeof(int);
  size_t off1 = (evbytes + 255) & ~(size_t)255;
  f16* frags = (f16*)(ws + off1);
  size_t off2 = off1 + ((60 * 512 * sizeof(f16) + 255) & ~(size_t)255);
  float* hpath = (float*)(ws + off2);

  hipMemsetAsync(evtab, 0, evbytes, stream);
  build_evtab_kernel<<<NE, 256, 0, stream>>>(sample_ids, time_ptr, evtab, B, OPE);
  pack_frags_kernel<<<60, 64, 0, stream>>>(ghr_W, ghz_W, ghh_W, gb_Whh, gb_Wih,
                                           frags, IN);
  evolve_kernel<<<(B + 15) / 16, 64, 0, stream>>>(
      time_uniq, X, covs, cov_W1, cov_b1, cov_W2, cov_b2,
      gb_bih, gb_bhh, gx_b, frags, evtab, hpath,
      B, NE, n_steps, IN, COV);
  long nrows = (long)(n_steps + 1) * B;
  int hb = (int)((nrows + 127) / 128);
  head_kernel<<<hb, 256, 0, stream>>>(hpath, out_W1, out_b1, out_W2, out_b2,
                                      (float*)d_out, nrows);
}

// Round 7
// 651.691 us; speedup vs baseline: 4.0375x; 4.0375x over previous
//
#include <hip/hip_runtime.h>

#define DT_F 0.01f
#define EPS_F 1e-5f
#define NEG_INF_I (-1073741824)

typedef _Float16 f16;
typedef _Float16 f16x2 __attribute__((ext_vector_type(2)));

__device__ __forceinline__ float rl(float v, int l) {
  return __int_as_float(__builtin_amdgcn_readlane(__float_as_int(v), l));
}
__device__ __forceinline__ float sigm(float x) { return 1.0f / (1.0f + __expf(-x)); }
__device__ __forceinline__ float tanhf_fast(float x) {
  float e = __expf(-2.0f * fabsf(x));
  float t = (1.0f - e) / (1.0f + e);
  return x < 0.0f ? -t : t;
}
// 2-wide f16 dot with fp32 accumulate: acc += w.lo*h.lo + w.hi*h.hi
__device__ __forceinline__ float dot2(unsigned w, unsigned h, float acc) {
  return __builtin_amdgcn_fdot2(__builtin_bit_cast(f16x2, w),
                                __builtin_bit_cast(f16x2, h), acc, false);
}
__device__ __forceinline__ unsigned packf16(float a, float b) {
  return __builtin_bit_cast(unsigned, __builtin_amdgcn_cvt_pkrtz(a, b));
}

// evtab[k*B + sid] = (last obs index in event k's window with sample_ids==sid) + 1, or 0.
__global__ void build_evtab_kernel(const int* __restrict__ sample_ids,
                                   const int* __restrict__ time_ptr,
                                   int* __restrict__ evtab, int B, int ope) {
  int k = blockIdx.x;
  int base = time_ptr[k];
  for (int t = threadIdx.x; t < ope; t += blockDim.x) {
    int obs = base + t;
    int sid = sample_ids[obs];
    atomicMax(&evtab[k * B + sid], obs + 1);   // last occurrence wins
  }
}

// Pack weight rows into f16-pair (u32) form:
//  odeP/bayP: [3][64][32] pairs, row r=g*64+i covers W[i][2p],W[i][2p+1]
//  wihP:      [3][64][4]  pairs (IN<=8, zero-padded)
__global__ void pack_pairs_kernel(const float* __restrict__ ghr,
                                  const float* __restrict__ ghz,
                                  const float* __restrict__ ghh,
                                  const float* __restrict__ gbWhh,
                                  const float* __restrict__ gbWih,
                                  unsigned* __restrict__ odeP,
                                  unsigned* __restrict__ bayP,
                                  unsigned* __restrict__ wihP, int IN) {
  int idx = blockIdx.x * 256 + threadIdx.x;
  if (idx < 3 * 64 * 32) {
    int p = idx & 31, r = idx >> 5;
    int g = r >> 6, i = r & 63;
    const float* src = (g == 0) ? ghr : ((g == 1) ? ghz : ghh);
    odeP[idx] = packf16(src[i * 64 + 2 * p], src[i * 64 + 2 * p + 1]);
    bayP[idx] = packf16(gbWhh[r * 64 + 2 * p], gbWhh[r * 64 + 2 * p + 1]);
  }
  if (idx < 3 * 64 * 4) {
    int p = idx & 3, r = idx >> 2;
    float a = (2 * p < IN) ? gbWih[r * IN + 2 * p] : 0.0f;
    float b = (2 * p + 1 < IN) ? gbWih[r * IN + 2 * p + 1] : 0.0f;
    wihP[idx] = packf16(a, b);
  }
}

// One wave per sample, 4 waves/block, 256 blocks, ZERO in-loop barriers.
// lane i owns h[i]. ODE weight rows as f16-pairs in VGPRs (96 regs);
// h / r*h broadcast via uniform-address ds_read_b128 of a 128B per-wave copy.
__global__ __launch_bounds__(256, 1) void evolve_kernel(
    const float* __restrict__ time_uniq,
    const float* __restrict__ X,
    const float* __restrict__ covs,
    const float* __restrict__ cov_W1, const float* __restrict__ cov_b1,
    const float* __restrict__ cov_W2, const float* __restrict__ cov_b2,
    const float* __restrict__ gb_bih, const float* __restrict__ gb_bhh,
    const float* __restrict__ gx_b,
    const unsigned* __restrict__ odeP, const unsigned* __restrict__ bayP,
    const unsigned* __restrict__ wihP,
    const int* __restrict__ evtab,
    float* __restrict__ hpath,
    int B, int NE, int n_steps, int IN, int COV)
{
  __shared__ unsigned sBW[3 * 64 * 32];          // Bayes pairs, slot-XOR swizzled (24KB)
  __shared__ int sStep[1024];                    // event e fires at grid step sStep[e]
  __shared__ __align__(16) f16 sH16[4][64];      // per-wave f16 copy of h
  __shared__ __align__(16) f16 sRH16[4][64];     // per-wave f16 copy of r*h

  const int tid = threadIdx.x;
  const int wid = tid >> 6, lane = tid & 63;
  const int b = blockIdx.x * 4 + wid;
  const bool alive = (b < B);

  // stage Bayes pairs with slot swizzle: slot' = slot ^ (row&7)
  for (int idx = tid; idx < 3 * 64 * 32; idx += 256) {
    int c = idx & 31, r = idx >> 5;
    int i = r & 63, s = c >> 2;
    sBW[r * 32 + (((s ^ (i & 7)) << 2) | (c & 3))] = bayP[idx];
  }
  // event schedule: wave-parallel prefix-max (verified R6)
  if (wid == 0) {
    int pm = NEG_INF_I;
    int loc[16];
#pragma unroll
    for (int j = 0; j < 16; ++j) {
      int e = lane * 16 + j;
      int gv = NEG_INF_I;
      if (e < NE && e < 1024) {
        float tu = time_uniq[e];
        int k0 = (int)floorf((tu - EPS_F) * 100.0f) - 2;
        if (k0 < 0) k0 = 0;
        while ((float)k0 * DT_F + EPS_F < tu) ++k0;   // exact fp32 semantics
        gv = k0 - e;
      }
      pm = max(pm, gv);
      loc[j] = pm;
    }
    int tot = pm;
#pragma unroll
    for (int off = 1; off < 64; off <<= 1) {
      int v = __shfl_up(tot, off);
      if (lane >= off) tot = max(tot, v);
    }
    int excl = __shfl_up(tot, 1);
    if (lane == 0) excl = NEG_INF_I;
#pragma unroll
    for (int j = 0; j < 16; ++j) {
      int e = lane * 16 + j;
      sStep[e] = e + max(loc[j], excl);
    }
  }
  __syncthreads();   // init only

  // ---- ODE weight rows into VGPRs: 3 x 8 x uint4 = 96 regs ----
  const uint4* odeQ = (const uint4*)odeP;
  uint4 WR[8], WZ[8], WU[8];
#pragma unroll
  for (int q = 0; q < 8; ++q) {
    WR[q] = odeQ[(0 * 64 + lane) * 8 + q];
    WZ[q] = odeQ[(1 * 64 + lane) * 8 + q];
    WU[q] = odeQ[(2 * 64 + lane) * 8 + q];
  }
  const uint4* wihQ = (const uint4*)wihP;
  const uint4 WXr = wihQ[lane], WXz = wihQ[64 + lane], WXn = wihQ[128 + lane];

  const float xr = gx_b[lane], xz = gx_b[64 + lane], xh = gx_b[128 + lane];
  const float crz_r = gb_bih[lane] + gb_bhh[lane];
  const float crz_z = gb_bih[64 + lane] + gb_bhh[64 + lane];
  const float bihn = gb_bih[128 + lane], bhhn = gb_bhh[128 + lane];

  // ---- h0 = tanh(relu(covs @ W1^T + b1) @ W2^T + b2) ----
  float h = 0.0f;
  if (alive) {
    float cacc = cov_b1[lane];
    for (int c = 0; c < COV; ++c)
      cacc = fmaf(covs[b * COV + c], cov_W1[lane * COV + c], cacc);
    float cl = fmaxf(cacc, 0.0f);
    float hacc = cov_b2[lane];
#pragma unroll
    for (int j = 0; j < 64; ++j)
      hacc = fmaf(rl(cl, j), cov_W2[lane * 64 + j], hacc);
    h = tanhf_fast(hacc);
  }
  sH16[wid][lane] = (f16)h;

  // ---- event pipeline (2-deep: v for e ready, v for e+1 in flight) ----
  int e_next = 0, s_next = 0x7fffffff, v_cur = 0, v_pipe = 0;
  float xf[8];
#pragma unroll
  for (int kk = 0; kk < 8; ++kk) xf[kk] = 0.0f;
  if (alive && NE > 0) {
    s_next = sStep[0];
    v_cur = evtab[b];
    if (v_cur > 0) {
      const float* xp = X + (long)(v_cur - 1) * IN;
#pragma unroll
      for (int kk = 0; kk < 8; ++kk) xf[kk] = (kk < IN) ? xp[kk] : 0.0f;
    }
    v_pipe = (NE > 1) ? evtab[B + b] : 0;
  } else if (NE > 0) {
    s_next = sStep[0];
  }

  const uint4* hq4 = (const uint4*)sH16[wid];
  const uint4* rq4 = (const uint4*)sRH16[wid];
  const long rowstride = (long)B * 64;
  const long hoff = (long)b * 64 + lane;

#pragma unroll 1
  for (int k = 0; k < n_steps; ++k) {
    if (k == s_next) {                       // wave-uniform
      if (v_cur > 0) {                       // this sample fires
        unsigned xp0 = packf16(xf[0], xf[1]), xp1 = packf16(xf[2], xf[3]);
        unsigned xp2 = packf16(xf[4], xf[5]), xp3 = packf16(xf[6], xf[7]);
        float ar = crz_r, az = crz_z, anh = bhhn, ani = bihn;
        ar = dot2(WXr.x, xp0, ar); ar = dot2(WXr.y, xp1, ar);
        ar = dot2(WXr.z, xp2, ar); ar = dot2(WXr.w, xp3, ar);
        az = dot2(WXz.x, xp0, az); az = dot2(WXz.y, xp1, az);
        az = dot2(WXz.z, xp2, az); az = dot2(WXz.w, xp3, az);
        ani = dot2(WXn.x, xp0, ani); ani = dot2(WXn.y, xp1, ani);
        ani = dot2(WXn.z, xp2, ani); ani = dot2(WXn.w, xp3, ani);
        const int rb_r = (0 * 64 + lane) * 32;
        const int rb_z = (1 * 64 + lane) * 32;
        const int rb_n = (2 * 64 + lane) * 32;
        float ar1 = 0.f, az1 = 0.f, an1 = 0.f;
#pragma unroll
        for (int q = 0; q < 8; ++q) {
          uint4 hp = hq4[q];
          int sw = ((q ^ (lane & 7)) << 2);
          uint4 br = *(const uint4*)&sBW[rb_r + sw];
          uint4 bz = *(const uint4*)&sBW[rb_z + sw];
          uint4 bn = *(const uint4*)&sBW[rb_n + sw];
          ar  = dot2(br.x, hp.x, ar);   ar1 = dot2(br.y, hp.y, ar1);
          ar  = dot2(br.z, hp.z, ar);   ar1 = dot2(br.w, hp.w, ar1);
          az  = dot2(bz.x, hp.x, az);   az1 = dot2(bz.y, hp.y, az1);
          az  = dot2(bz.z, hp.z, az);   az1 = dot2(bz.w, hp.w, az1);
          anh = dot2(bn.x, hp.x, anh);  an1 = dot2(bn.y, hp.y, an1);
          anh = dot2(bn.z, hp.z, anh);  an1 = dot2(bn.w, hp.w, an1);
        }
        float r = sigm(ar + ar1);
        float z = sigm(az + az1);
        float n = tanhf_fast(ani + r * (anh + an1));
        h = (1.0f - z) * n + z * h;
        sH16[wid][lane] = (f16)h;
      }
      ++e_next;
      if (e_next < NE && e_next < 1024) {
        s_next = sStep[e_next];
        v_cur = v_pipe;                      // arrived (issued one event ago)
        if (v_cur > 0) {
          const float* xp = X + (long)(v_cur - 1) * IN;
#pragma unroll
          for (int kk = 0; kk < 8; ++kk) xf[kk] = (kk < IN) ? xp[kk] : 0.0f;
        }
        v_pipe = (e_next + 1 < NE) ? evtab[(long)(e_next + 1) * B + b] : 0;
      } else {
        s_next = 0x7fffffff;
        v_cur = 0;
      }
    }

    if (alive)
      hpath[(long)k * rowstride + hoff] = h;   // h_rec (post-event, pre-ODE)

    // ---- phase A: r,z gates (weights in VGPR, h-pairs broadcast from LDS) ----
    float ar0 = xr, ar1 = 0.f, ar2 = 0.f, ar3 = 0.f;
    float az0 = xz, az1 = 0.f, az2 = 0.f, az3 = 0.f;
#pragma unroll
    for (int q = 0; q < 8; ++q) {
      uint4 hp = hq4[q];
      ar0 = dot2(WR[q].x, hp.x, ar0); ar1 = dot2(WR[q].y, hp.y, ar1);
      ar2 = dot2(WR[q].z, hp.z, ar2); ar3 = dot2(WR[q].w, hp.w, ar3);
      az0 = dot2(WZ[q].x, hp.x, az0); az1 = dot2(WZ[q].y, hp.y, az1);
      az2 = dot2(WZ[q].z, hp.z, az2); az3 = dot2(WZ[q].w, hp.w, az3);
    }
    float r = sigm((ar0 + ar1) + (ar2 + ar3));
    float z = sigm((az0 + az1) + (az2 + az3));
    sRH16[wid][lane] = (f16)(r * h);

    // ---- phase B: u matvec (r*h pairs broadcast) ----
    float au0 = xh, au1 = 0.f, au2 = 0.f, au3 = 0.f;
#pragma unroll
    for (int q = 0; q < 8; ++q) {
      uint4 rp = rq4[q];
      au0 = dot2(WU[q].x, rp.x, au0); au1 = dot2(WU[q].y, rp.y, au1);
      au2 = dot2(WU[q].z, rp.z, au2); au3 = dot2(WU[q].w, rp.w, au3);
    }
    float u = tanhf_fast((au0 + au1) + (au2 + au3));
    h = fmaf(DT_F * (1.0f - z), u - h, h);
    sH16[wid][lane] = (f16)h;
  }

  if (alive)
    hpath[(long)n_steps * rowstride + hoff] = h;   // h_last
}

// out[row] = relu(h[row] @ W1^T + b1) @ W2^T + b2, rows = (n_steps+1)*B
__global__ __launch_bounds__(256, 2) void head_kernel(
    const float* __restrict__ hpath, const float* __restrict__ W1,
    const float* __restrict__ b1, const float* __restrict__ W2,
    const float* __restrict__ b2, float* __restrict__ out, long nrows)
{
  __shared__ __align__(16) float sW1[64 * 128];
  __shared__ __align__(16) float sH[64 * 128];
  int tid = threadIdx.x;
  for (int idx = tid; idx < 128 * 64; idx += 256) {
    int oc = idx >> 6, j = idx & 63;
    sW1[j * 128 + oc] = W1[idx];
  }
  long row0 = (long)blockIdx.x * 128;
  for (int idx = tid; idx < 128 * 64; idx += 256) {
    int r = idx >> 6, j = idx & 63;
    long row = row0 + r;
    sH[j * 128 + r] = (row < nrows) ? hpath[row * 64 + j] : 0.0f;
  }
  __syncthreads();

  int tr = tid >> 4, tc = tid & 15;
  int r0 = tr * 8, oc0 = tc * 8;
  float acc[8][8];
#pragma unroll
  for (int s = 0; s < 8; ++s)
#pragma unroll
    for (int u = 0; u < 8; ++u) acc[s][u] = 0.0f;

#pragma unroll 4
  for (int j = 0; j < 64; ++j) {
    float4 ha = *(const float4*)&sH[j * 128 + r0];
    float4 hb = *(const float4*)&sH[j * 128 + r0 + 4];
    float4 wa = *(const float4*)&sW1[j * 128 + oc0];
    float4 wb = *(const float4*)&sW1[j * 128 + oc0 + 4];
    float hv[8] = {ha.x, ha.y, ha.z, ha.w, hb.x, hb.y, hb.z, hb.w};
    float wv[8] = {wa.x, wa.y, wa.z, wa.w, wb.x, wb.y, wb.z, wb.w};
#pragma unroll
    for (int s = 0; s < 8; ++s)
#pragma unroll
      for (int u = 0; u < 8; ++u)
        acc[s][u] = fmaf(hv[s], wv[u], acc[s][u]);
  }

  float p[8][2];
#pragma unroll
  for (int s = 0; s < 8; ++s) { p[s][0] = 0.0f; p[s][1] = 0.0f; }
#pragma unroll
  for (int u = 0; u < 8; ++u) {
    float b1v = b1[oc0 + u];
    float w2a = W2[oc0 + u];
    float w2b = W2[128 + oc0 + u];
#pragma unroll
    for (int s = 0; s < 8; ++s) {
      float o = fmaxf(acc[s][u] + b1v, 0.0f);
      p[s][0] = fmaf(o, w2a, p[s][0]);
      p[s][1] = fmaf(o, w2b, p[s][1]);
    }
  }
#pragma unroll
  for (int off = 1; off < 16; off <<= 1) {
#pragma unroll
    for (int s = 0; s < 8; ++s) {
      p[s][0] += __shfl_xor(p[s][0], off);
      p[s][1] += __shfl_xor(p[s][1], off);
    }
  }
  if (tc == 0) {
    float b20 = b2[0], b21 = b2[1];
#pragma unroll
    for (int s = 0; s < 8; ++s) {
      long row = row0 + r0 + s;
      if (row < nrows) {
        out[row * 2 + 0] = p[s][0] + b20;
        out[row * 2 + 1] = p[s][1] + b21;
      }
    }
  }
}

extern "C" void kernel_launch(void* const* d_in, const int* in_sizes, int n_in,
                              void* d_out, int out_size, void* d_ws, size_t ws_size,
                              hipStream_t stream) {
  const float* time_uniq  = (const float*)d_in[0];
  const int*   time_ptr   = (const int*)d_in[1];
  const float* X          = (const float*)d_in[2];
  const int*   sample_ids = (const int*)d_in[3];
  const float* covs       = (const float*)d_in[4];
  const float* cov_W1     = (const float*)d_in[6];
  const float* cov_b1     = (const float*)d_in[7];
  const float* cov_W2     = (const float*)d_in[8];
  const float* cov_b2     = (const float*)d_in[9];
  const float* gb_Wih     = (const float*)d_in[10];
  const float* gb_Whh     = (const float*)d_in[11];
  const float* gb_bih     = (const float*)d_in[12];
  const float* gb_bhh     = (const float*)d_in[13];
  const float* gx_b       = (const float*)d_in[15];
  const float* ghr_W      = (const float*)d_in[16];
  const float* ghz_W      = (const float*)d_in[17];
  const float* ghh_W      = (const float*)d_in[18];
  const float* out_W1     = (const float*)d_in[19];
  const float* out_b1     = (const float*)d_in[20];
  const float* out_W2     = (const float*)d_in[21];
  const float* out_b2     = (const float*)d_in[22];

  int NE   = in_sizes[0];
  int TOT  = in_sizes[3];
  int IN   = in_sizes[2] / TOT;
  int CH   = in_sizes[7];
  int COV  = in_sizes[6] / CH;
  int B    = in_sizes[4] / COV;
  int OUTD = in_sizes[22];
  int n_steps = out_size / (B * OUTD) - 1;
  int OPE  = TOT / NE;

  char* ws = (char*)d_ws;
  int* evtab = (int*)ws;
  size_t evbytes = (size_t)NE * (size_t)B * sizeof(int);
  size_t off1 = (evbytes + 255) & ~(size_t)255;
  unsigned* odeP = (unsigned*)(ws + off1);
  unsigned* bayP = odeP + 3 * 64 * 32;
  unsigned* wihP = bayP + 3 * 64 * 32;
  size_t off2 = off1 + (((3 * 64 * 32 * 2 + 3 * 64 * 4) * sizeof(unsigned) + 255) & ~(size_t)255);
  float* hpath = (float*)(ws + off2);

  hipMemsetAsync(evtab, 0, evbytes, stream);
  build_evtab_kernel<<<NE, 256, 0, stream>>>(sample_ids, time_ptr, evtab, B, OPE);
  pack_pairs_kernel<<<24, 256, 0, stream>>>(ghr_W, ghz_W, ghh_W, gb_Whh, gb_Wih,
                                            odeP, bayP, wihP, IN);
  evolve_kernel<<<(B + 3) / 4, 256, 0, stream>>>(
      time_uniq, X, covs, cov_W1, cov_b1, cov_W2, cov_b2,
      gb_bih, gb_bhh, gx_b, odeP, bayP, wihP,
      evtab, hpath, B, NE, n_steps, IN, COV);
  long nrows = (long)(n_steps + 1) * B;
  int hb = (int)((nrows + 127) / 128);
  head_kernel<<<hb, 256, 0, stream>>>(hpath, out_W1, out_b1, out_W2, out_b2,
                                      (float*)d_out, nrows);
}